// Round 12
// baseline (394.615 us; speedup 1.0000x reference)
//
#include <hip/hip_runtime.h>
#include <cstdint>

// AdaptiveLoss: adaptive-softmax NLL.  4 launches:
//   1. cvt_bf16   : f32->bf16 for all operands (10 segments, 4096 blocks).
//   2. gemm_all   : proj GEMMs (bf16 C -> Hact), grid (8,8).
//   3. gemm_all   : single mega (head + c0..c3, 6280 blocks) -> sum-exp
//                   partials part[row][785] (flat per-row) + head gates.
//   4. gather_rows: in-block LSE + cluster-sorted targets + exact-trip dots
//                   + fused row loss + atomic final accumulation into out.
// R12 = R11 resubmitted verbatim (R11 bench was GPUAcquisitionTimeout --
// infra failure, no data). Changes vs R9 (292.1 best):
//  - mega: msLds overlaid on ldsA (dead after K-loop; fenced by an extra
//    barrier) -> LDS exactly 32768 B -> 5 blocks/CU via launch_bounds(256,5)
//    (was 4): more cross-block overlap during the per-block barrier drains.
//  - final_sum deleted: gather atomicAdds psamp/(1024+1e-5) into out
//    (zeroed by hipMemsetAsync; device-scope atomics are XCD-safe).

typedef unsigned short u16;
typedef __attribute__((ext_vector_type(4))) float f32x4;
typedef __attribute__((ext_vector_type(8))) __bf16 bf16x8;
typedef __attribute__((ext_vector_type(4))) unsigned int u32x4;

__device__ __forceinline__ u16 f2bf(float f){
  unsigned u = __float_as_uint(f);
  u += 0x7FFFu + ((u >> 16) & 1u);   // RNE
  return (u16)(u >> 16);
}

__device__ __forceinline__ float wave_sum(float v){
  #pragma unroll
  for (int d = 1; d < 64; d <<= 1) v += __shfl_xor(v, d, 64);
  return v;
}

// async global->LDS, 16B per lane. LDS dest must be wave-uniform base
// (HW adds lane*16); global src is per-lane (carries the XOR pre-swizzle).
__device__ __forceinline__ void gload_lds16(const void* g, void* l){
  __builtin_amdgcn_global_load_lds(
      (const __attribute__((address_space(1))) unsigned int*)g,
      (__attribute__((address_space(3))) unsigned int*)l, 16, 0, 0);
}

// ---------------- convert f32 -> bf16 (10 segments, one launch) ----------------
struct CvtSeg { const float* src; u16* dst; unsigned start; }; // start in 8-elem chunks
struct CvtTab { CvtSeg s[10]; unsigned total; };

__global__ __launch_bounds__(256) void cvt_bf16(CvtTab t){
  unsigned stride = gridDim.x * blockDim.x;
  for (unsigned c = blockIdx.x*blockDim.x + threadIdx.x; c < t.total; c += stride){
    int si = 0;
    #pragma unroll
    for (int i = 1; i < 10; i++) if (c >= t.s[i].start) si = i;
    unsigned lo = c - t.s[si].start;
    const float4* sp = (const float4*)t.s[si].src + (size_t)lo*2;
    float4 f0 = sp[0], f1 = sp[1];
    uint4 d;
    d.x = (unsigned)f2bf(f0.x) | ((unsigned)f2bf(f0.y) << 16);
    d.y = (unsigned)f2bf(f0.z) | ((unsigned)f2bf(f0.w) << 16);
    d.z = (unsigned)f2bf(f1.x) | ((unsigned)f2bf(f1.y) << 16);
    d.w = (unsigned)f2bf(f1.z) | ((unsigned)f2bf(f1.w) << 16);
    ((uint4*)t.s[si].dst)[lo] = d;
  }
}

// ------- unified GEMM: C = A[MxK] * B[NxK]^T, 128x128 tile, BK=64 -------
// 4 waves 2x2; global_load_lds staging. part!=null -> per-(row,tile) sum-exp
// partials, layout part[row*ldc + tileN] (ldc = 785 global row stride, part
// pre-offset by the segment's global tile base); else bf16 C store (ldc).
// gates!=null (head): cols>=10000 -> gates[row*4+i].
// LDS exactly 32KB (msLds overlaid on ldsA post-K-loop) -> 5 blocks/CU.
struct GSeg { const u16* A; const u16* B; float* part; u16* C; float* gates;
              int lda, N, K, ntiles, tileStart, ldc; };
struct GTab { GSeg seg[5]; int nseg; int swz; };

__global__ __launch_bounds__(256, 5) void gemm_all(GTab tab){
  __shared__ __attribute__((aligned(16))) u16 ldsA[128*64];
  __shared__ __attribute__((aligned(16))) u16 ldsB[128*64];

  int bx = blockIdx.x, by = blockIdx.y;
  if (tab.swz){
    // bijective XCD swizzle, grid (8, nby): hardware XCD ~ flat%8.
    int flat = by * 8 + bx;
    int xcd = flat & 7, j = flat >> 3;
    by = (j >> 3) * 8 + xcd;
    bx = j & 7;
    if (by >= (int)gridDim.y){ by = j; bx = xcd; }  // bijective tail patch
  }

  int s = 0;
  #pragma unroll
  for (int i = 1; i < 5; i++)
    if (i < tab.nseg && by >= tab.seg[i].tileStart) s = i;
  const u16* Ab = tab.seg[s].A;
  const u16* Bb = tab.seg[s].B;
  float* part   = tab.seg[s].part;
  u16* Cc       = tab.seg[s].C;
  float* gatesp = tab.seg[s].gates;
  int lda = tab.seg[s].lda, N = tab.seg[s].N, K = tab.seg[s].K;
  int ldc = tab.seg[s].ldc;
  int tileN = by - tab.seg[s].tileStart;
  int n0 = tileN * 128;
  int row0 = bx * 128;

  int tid = threadIdx.x;
  int wid = tid >> 6, lane = tid & 63;
  int wr = wid >> 1, wc = wid & 1;
  int qr = lane >> 4, ln = lane & 15;

  // staging: 1024 chunks (16B) per matrix, 4 per thread; XOR swizzle applied
  // to the GLOBAL source k-chunk, LDS written linearly.
  const char* baseA = (const char*)(Ab + (size_t)row0*lda);
  const char* baseB = (const char*)Bb;
  unsigned offA[4], offB[4];
  #pragma unroll
  for (int t = 0; t < 4; t++){
    int c = t*256 + tid, row = c >> 3, jj = (c & 7) ^ (row & 7);
    offA[t] = (unsigned)(row*lda + jj*8) * 2u;
    int nr = n0 + row; if (nr >= N) nr = N - 1;    // clamp; masked in epilogue
    offB[t] = (unsigned)(nr*K + jj*8) * 2u;
  }

  f32x4 acc[4][4];
  const f32x4 zero = {0.f, 0.f, 0.f, 0.f};
  #pragma unroll
  for (int i = 0; i < 4; i++)
    #pragma unroll
    for (int j = 0; j < 4; j++) acc[i][j] = zero;

  int nkt = K >> 6;
  for (int kt = 0; kt < nkt; kt++){
    __syncthreads();                       // previous compute done
    unsigned kb = (unsigned)kt * 128u;
    #pragma unroll
    for (int t = 0; t < 4; t++){
      gload_lds16(baseA + offA[t] + kb, (char*)ldsA + (size_t)(t*256 + tid)*16);
      gload_lds16(baseB + offB[t] + kb, (char*)ldsB + (size_t)(t*256 + tid)*16);
    }
    __syncthreads();                       // compiler drains vmcnt(0) here
    #pragma unroll
    for (int ks = 0; ks < 2; ks++){
      bf16x8 av[4], bv[4];
      #pragma unroll
      for (int mt = 0; mt < 4; mt++){
        int rl = wr*64 + mt*16 + ln;
        int ch = rl*8 + ((ks*4 + qr) ^ (rl & 7));
        av[mt] = *(const bf16x8*)((const char*)ldsA + ch*16);
      }
      #pragma unroll
      for (int nt = 0; nt < 4; nt++){
        int rl = wc*64 + nt*16 + ln;
        int ch = rl*8 + ((ks*4 + qr) ^ (rl & 7));
        bv[nt] = *(const bf16x8*)((const char*)ldsB + ch*16);
      }
      #pragma unroll
      for (int mt = 0; mt < 4; mt++)
        #pragma unroll
        for (int nt = 0; nt < 4; nt++)
          acc[mt][nt] = __builtin_amdgcn_mfma_f32_16x16x32_bf16(av[mt], bv[nt], acc[mt][nt], 0, 0, 0);
    }
  }

  if (part){
    __syncthreads();                       // all ldsA reads done: overlay safe
    float (*msLds)[2] = (float(*)[2])ldsA; // reuse dead ldsA for 128x2 floats
    // C layout: row = quad*4 + reg, col = lane&15 (per 16x16 tile). Plain sum-exp.
    #pragma unroll
    for (int mt = 0; mt < 4; mt++){
      #pragma unroll
      for (int r = 0; r < 4; r++){
        float ss = 0.f;
        #pragma unroll
        for (int nt = 0; nt < 4; nt++){
          int col = n0 + wc*64 + nt*16 + ln;
          if (col < N){
            float v = acc[mt][nt][r];
            ss += __expf(v);
            if (gatesp && col >= 10000){
              int row = row0 + wr*64 + mt*16 + qr*4 + r;
              gatesp[row*4 + (col - 10000)] = v;
            }
          }
        }
        ss += __shfl_xor(ss, 1, 64);
        ss += __shfl_xor(ss, 2, 64);
        ss += __shfl_xor(ss, 4, 64);
        ss += __shfl_xor(ss, 8, 64);
        if (ln == 0) msLds[wr*64 + mt*16 + qr*4 + r][wc] = ss;
      }
    }
    __syncthreads();
    if (tid < 128)
      part[(size_t)(row0 + tid)*ldc + tileN] = msLds[tid][0] + msLds[tid][1];
  } else {
    #pragma unroll
    for (int mt = 0; mt < 4; mt++)
      #pragma unroll
      for (int nt = 0; nt < 4; nt++)
        #pragma unroll
        for (int r = 0; r < 4; r++){
          int col = n0 + wc*64 + nt*16 + ln;
          if (col < N){
            int row = row0 + wr*64 + mt*16 + qr*4 + r;
            Cc[(size_t)row*ldc + col] = f2bf(acc[mt][nt][r]);
          }
        }
  }
}

// ---- gather helpers: exact-trip unrolled dots (16-lane group, 128 elems/iter) ----
__device__ __forceinline__ float dot8pair(u32x4 va, u32x4 vb){
  float p = 0.f;
  #pragma unroll
  for (int i = 0; i < 4; i++){
    unsigned ua = va[i], ub = vb[i];
    p = fmaf(__uint_as_float(ua << 16),         __uint_as_float(ub << 16),         p);
    p = fmaf(__uint_as_float(ua & 0xFFFF0000u), __uint_as_float(ub & 0xFFFF0000u), p);
  }
  return p;
}

template<int T>
__device__ __forceinline__ float dotT(const u16* a, const u16* b, int gl){
  float s = 0.f;
  #pragma unroll
  for (int it = 0; it < T; it++){
    int k = gl*8 + it*128;
    s += dot8pair(*(const u32x4*)(a + k), *(const u32x4*)(b + k));
  }
  return s;
}

// len=64 variant: one iteration, upper 8 lanes masked
__device__ __forceinline__ float dot1m(const u16* a, const u16* b, int gl){
  int k = gl*8;
  int kc = k < 64 ? k : 0;
  float p = dot8pair(*(const u32x4*)(a + kc), *(const u32x4*)(b + kc));
  return k < 64 ? p : 0.f;
}

// ------- row-centric: in-block LSE + sorted per-target log-prob + row loss -------
// part is flat [1024 rows][785 global tiles]; segment boundaries within a row:
// head 0..78, c0 79..157, c1 158..314, c2 315..627, c3 628..784.
// Final loss accumulated atomically into out (out pre-zeroed).
struct GatherArgs {
  const u16* Xb; const u16* Hb; const u16* Hact; const u16* Ob;
  const float* part; const float* gates; const int* targets;
  const float* discard; float* out;
};

__global__ __launch_bounds__(256) void gather_rows(GatherArgs g){
  __shared__ __attribute__((aligned(16))) u16 xr[1024];
  __shared__ __attribute__((aligned(16))) u16 hr[960];
  __shared__ __attribute__((aligned(16))) int tg[128];
  __shared__ int tgs[128];                // cluster-sorted targets
  __shared__ int cntW[2][5];              // per-wave bucket counts
  __shared__ float sLse[4][5];
  __shared__ float ls[5], gs[4];
  __shared__ float lpv[128];
  __shared__ float sa[2], sw[2];

  int b = blockIdx.x;
  int tid = threadIdx.x;
  int w = tid >> 6, lane = tid & 63;
  int grp = tid >> 4, gl = tid & 15;      // 16 groups x 16 lanes

  if (tid < 128) ((u32x4*)xr)[tid] = ((const u32x4*)(g.Xb + (size_t)b*1024))[tid];
  else if (tid < 248) ((u32x4*)hr)[tid-128] = ((const u32x4*)(g.Hact + (size_t)b*960))[tid-128];
  if (tid < 32) ((u32x4*)tg)[tid] = ((const u32x4*)(g.targets + (size_t)b*128))[tid];
  if (tid < 4) gs[tid] = g.gates[b*4 + tid];

  // in-block LSE: contiguous coalesced read of this row's 785 partials
  {
    const float* pr = g.part + (size_t)b*785;
    float p0=0.f, p1=0.f, p2=0.f, p3=0.f, p4=0.f;
    for (int j = tid; j < 785; j += 256){
      float v = pr[j];
      if      (j <  79) p0 += v;
      else if (j < 158) p1 += v;
      else if (j < 315) p2 += v;
      else if (j < 628) p3 += v;
      else              p4 += v;
    }
    p0 = wave_sum(p0); p1 = wave_sum(p1); p2 = wave_sum(p2);
    p3 = wave_sum(p3); p4 = wave_sum(p4);
    if (lane == 0){
      sLse[w][0]=p0; sLse[w][1]=p1; sLse[w][2]=p2; sLse[w][3]=p3; sLse[w][4]=p4;
    }
  }
  __syncthreads();                        // staging + sLse visible
  if (tid < 5)
    ls[tid] = __logf(sLse[0][tid] + sLse[1][tid] + sLse[2][tid] + sLse[3][tid]);

  // ---- counting sort by bucket (ballot/popcount); waves 2,3 mirror harmlessly ----
  int vb128 = tg[tid & 127];
  int bkt = (vb128 >= 10000) + (vb128 >= 20000) + (vb128 >= 40000) + (vb128 >= 80000);
  unsigned long long ltm = (1ULL << lane) - 1ULL;
  int rank = 0;
  #pragma unroll
  for (int c = 0; c < 5; c++){
    unsigned long long m = __ballot(bkt == c);
    if (bkt == c) rank = __popcll(m & ltm);
    if (lane == 0 && w < 2) cntW[w][c] = (int)__popcll(m);
  }
  __syncthreads();                        // cntW + ls visible
  if (tid < 128){
    int base = 0;
    #pragma unroll
    for (int c = 0; c < 5; c++)
      base += (c < bkt) ? (cntW[0][c] + cntW[1][c]) : 0;
    int pos = base + (w == 1 ? cntW[0][bkt] : 0) + rank;
    tgs[pos] = vb128;
  }
  __syncthreads();                        // tgs visible

  // ---- per-target log-prob: 16 consecutive sorted targets per iteration ----
  for (int t = 0; t < 8; t++){
    int ti = t*16 + grp;
    int v = tgs[ti];                      // group-uniform; wave-uniform cluster (sorted)
    bool head = v < 10000;
    int c = (v >= 20000) + (v >= 40000) + (v >= 80000);
    float s;
    if (head)       s = dotT<8>(xr,       g.Hb + (size_t)v*1024, gl);
    else if (c==0)  s = dotT<4>(hr,       g.Ob + (size_t)(v-10000)*512, gl);
    else if (c==1)  s = dotT<2>(hr + 512, g.Ob + 5120000u  + (size_t)(v-20000)*256, gl);
    else if (c==2)  s = dotT<1>(hr + 768, g.Ob + 10240000u + (size_t)(v-40000)*128, gl);
    else            s = dot1m  (hr + 896, g.Ob + 15360000u + (size_t)(v-80000)*64,  gl);
    // 16-lane group reduce (xor < 16 stays inside the group)
    s += __shfl_xor(s, 1, 64);
    s += __shfl_xor(s, 2, 64);
    s += __shfl_xor(s, 4, 64);
    s += __shfl_xor(s, 8, 64);
    float bias = head ? -ls[0] : (gs[c] - ls[0] - ls[c + 1]);   // LDS dyn-index ok
    if (gl == 0) lpv[ti] = s + bias;
  }
  __syncthreads();

  // fused row_loss: per-row weighted mean NLL; atomic final accumulation
  if (tid < 128){
    int v = tgs[tid];
    float wt = 1.0f - g.discard[v];
    float a  = -lpv[tid] * wt;
    float as = wave_sum(a), ws = wave_sum(wt);
    if (lane == 0){ sa[w] = as; sw[w] = ws; }
  }
  __syncthreads();
  if (tid == 0){
    float ps = (sa[0] + sa[1]) / (sw[0] + sw[1]);
    atomicAdd(g.out, ps * (1.0f / (1024.0f + 1e-5f)));
  }
}

// ---------------- host ----------------
extern "C" void kernel_launch(void* const* d_in, const int* in_sizes, int n_in,
                              void* d_out, int out_size, void* d_ws, size_t ws_size,
                              hipStream_t stream){
  (void)in_sizes; (void)n_in; (void)out_size; (void)ws_size;
  const float* features = (const float*)d_in[0];
  const float* head_w   = (const float*)d_in[1];
  const float* proj[4]  = {(const float*)d_in[2], (const float*)d_in[4],
                           (const float*)d_in[6], (const float*)d_in[8]};
  const float* outw[4]  = {(const float*)d_in[3], (const float*)d_in[5],
                           (const float*)d_in[7], (const float*)d_in[9]};
  const float* discard  = (const float*)d_in[10];
  const int*   targets  = (const int*)d_in[11];
  float* out = (float*)d_out;

  char* wsp = (char*)d_ws;
  size_t off = 0;
  auto carve = [&](size_t bytes)->char*{
    char* p = wsp + off; off += (bytes + 255) & ~(size_t)255; return p;
  };
  u16* Xb     = (u16*)carve(1024ull*1024*2);
  u16* Hb     = (u16*)carve(10004ull*1024*2);
  u16* Pb     = (u16*)carve(960ull*1024*2);
  u16* Ob     = (u16*)carve(16640000ull*2);
  u16* Hact   = (u16*)carve(1024ull*960*2);
  float* part = (float*)carve(803840ull*4);   // 1024 rows x 785 global tiles
  float* gates= (float*)carve(4096*4);

  // zero the output accumulator (graph-capture-safe async memset)
  hipMemsetAsync(out, 0, sizeof(float), stream);

  // launch 1: convert all f32 operands to bf16
  CvtTab ct{};
  const float* srcs[10] = {features, head_w, proj[0], proj[1], proj[2], proj[3],
                           outw[0], outw[1], outw[2], outw[3]};
  u16* dsts[10] = {Xb, Hb, Pb, Pb + 512*1024, Pb + 768*1024, Pb + 896*1024,
                   Ob, Ob + 5120000, Ob + 10240000, Ob + 15360000};
  unsigned counts[10] = {1048576u, 10244096u, 524288u, 262144u, 131072u, 65536u,
                         5120000u, 5120000u, 5120000u, 1280000u};
  unsigned pre = 0;
  for (int i = 0; i < 10; i++){
    ct.s[i].src = srcs[i]; ct.s[i].dst = dsts[i]; ct.s[i].start = pre;
    pre += counts[i] / 8;
  }
  ct.total = pre;  // 3,614,464 chunks
  cvt_bf16<<<dim3(4096), dim3(256), 0, stream>>>(ct);

  // launch 2: proj GEMMs (bf16 C -> Hact); small, must precede cluster segs
  GTab tp{};
  tp.nseg = 4; tp.swz = 0;
  tp.seg[0] = {Xb, Pb,            nullptr, Hact,       nullptr, 1024, 512, 1024, 4, 0, 960};
  tp.seg[1] = {Xb, Pb + 512*1024, nullptr, Hact + 512, nullptr, 1024, 256, 1024, 2, 4, 960};
  tp.seg[2] = {Xb, Pb + 768*1024, nullptr, Hact + 768, nullptr, 1024, 128, 1024, 1, 6, 960};
  tp.seg[3] = {Xb, Pb + 896*1024, nullptr, Hact + 896, nullptr, 1024, 64,  1024, 1, 7, 960};
  gemm_all<<<dim3(8, 8), dim3(256), 0, stream>>>(tp);

  // launch 3: mega — head + all 4 cluster GEMMs, 6280 blocks.
  // part[row][785]: per-seg pointer = part + global tile base; ldc = 785.
  GTab tm{};
  tm.nseg = 5; tm.swz = 1;
  tm.seg[0] = {Xb,         Hb,            part,       nullptr, gates,   1024, 10004, 1024, 79,  0,   785};
  tm.seg[1] = {Hact,       Ob,            part + 79,  nullptr, nullptr, 960,  10000, 512,  79,  79,  785};
  tm.seg[2] = {Hact + 512, Ob + 5120000,  part + 158, nullptr, nullptr, 960,  20000, 256,  157, 158, 785};
  tm.seg[3] = {Hact + 768, Ob + 10240000, part + 315, nullptr, nullptr, 960,  40000, 128,  313, 315, 785};
  tm.seg[4] = {Hact + 896, Ob + 15360000, part + 628, nullptr, nullptr, 960,  20000, 64,   157, 628, 785};
  gemm_all<<<dim3(8, 785), dim3(256), 0, stream>>>(tm);

  // launch 4: gather (in-block LSE + sorted target log-probs + row loss +
  // atomic final accumulation)
  GatherArgs ga{Xb, Hb, Hact, Ob, part, gates, targets, discard, out};
  gather_rows<<<dim3(1024), dim3(256), 0, stream>>>(ga);
}